// Round 4
// baseline (150.468 us; speedup 1.0000x reference)
//
#include <hip/hip_runtime.h>
#include <hip/hip_bf16.h>

typedef unsigned short u16;
typedef __attribute__((ext_vector_type(8))) short short8;
typedef __attribute__((ext_vector_type(4))) float f32x4;

#define MFMA16(a,b,c) __builtin_amdgcn_mfma_f32_16x16x32_bf16(a,b,c,0,0,0)

__device__ __forceinline__ u16 f2bf(float x){
  union { float f; unsigned u; } v; v.f = x;
  unsigned r = v.u + 0x7FFFu + ((v.u >> 16) & 1u);   // RTNE
  return (u16)(r >> 16);
}

// =============== kPrep: fused W1-permute + W2 transpose + GEMM3 ===========
// blocks 0..319   : W1[320][2048] f32 -> w1bp bf16 in MFMA-fragment order
//                   gid -> (kseg, f, l); elem j: B[f*16+(l&15)][kseg*32+(l>>4)*8+j]
// blocks 320..639 : W2[1000][320] -> W2T[320][1024] zero-padded
// blocks 640..767 : l3p[kg][64][1024] = feat @ W3^T split-K partials
__global__ __launch_bounds__(256) void kprep(
    const float* __restrict__ W1, const float* __restrict__ W2,
    const float* __restrict__ feat, const float* __restrict__ W3,
    u16* __restrict__ w1bp, float* __restrict__ W2T, float* __restrict__ l3p)
{
  __shared__ float tile[32][33];
  const int bid = blockIdx.x;
  const int t = threadIdx.x;

  if (bid < 320){
    int gid = bid * 256 + t;
    int kseg = gid / 1280;
    int rem = gid - kseg * 1280;
    int f = rem >> 6, l = rem & 63;
    int row = f * 16 + (l & 15);
    int col = kseg * 32 + (l >> 4) * 8;
    const float4* s = (const float4*)(W1 + (size_t)row * 2048 + col);
    float4 a = s[0], b = s[1];
    short8 pk;
    pk[0]=(short)f2bf(a.x); pk[1]=(short)f2bf(a.y); pk[2]=(short)f2bf(a.z); pk[3]=(short)f2bf(a.w);
    pk[4]=(short)f2bf(b.x); pk[5]=(short)f2bf(b.y); pk[6]=(short)f2bf(b.z); pk[7]=(short)f2bf(b.w);
    *(short8*)(w1bp + (size_t)gid * 8) = pk;
  } else if (bid < 640){
    const int bb = bid - 320;
    const int tx = t & 31, ty = t >> 5;          // 32 x 8
    const int bx = bb & 31;                      // c tile (32 -> 1024)
    const int by = bb >> 5;                      // a tile (10 -> 320)
#pragma unroll
    for (int k = 0; k < 4; ++k){
      int c = bx*32 + ty + k*8;
      int a = by*32 + tx;
      tile[ty + k*8][tx] = (c < 1000) ? W2[(size_t)c*320 + a] : 0.f;
    }
    __syncthreads();
#pragma unroll
    for (int k = 0; k < 4; ++k){
      int a = by*32 + ty + k*8;
      int c = bx*32 + tx;
      W2T[(size_t)a*1024 + c] = tile[tx][ty + k*8];
    }
  } else {
    const int bb = bid - 640;
    const int kg = bb & 7;     // K chunk of 256
    const int cg = bb >> 3;    // 16 c-groups of 64
    const int w = t >> 6, b = t & 63;
    const int cbase = cg*64 + w*16;
    float carr[16];
#pragma unroll
    for (int i = 0; i < 16; ++i) carr[i] = 0.f;
#pragma unroll
    for (int h = 0; h < 2; ++h){
      const float4* f4 = (const float4*)(feat + (size_t)b*2048 + kg*256 + h*128);
      float4 fr[32];
#pragma unroll
      for (int j = 0; j < 32; ++j) fr[j] = f4[j];
      for (int ci = 0; ci < 16; ++ci){
        int c = cbase + ci;
        if (c >= 1000) break;
        const float4* w4 = (const float4*)(W3 + (size_t)c*2048 + kg*256 + h*128);
        float a0=0.f, a1=0.f, a2=0.f, a3=0.f;
#pragma unroll
        for (int j = 0; j < 32; j += 4){
          float4 x0=fr[j],   y0=w4[j];
          float4 x1=fr[j+1], y1=w4[j+1];
          float4 x2=fr[j+2], y2=w4[j+2];
          float4 x3=fr[j+3], y3=w4[j+3];
          a0 += x0.x*y0.x + x0.y*y0.y + x0.z*y0.z + x0.w*y0.w;
          a1 += x1.x*y1.x + x1.y*y1.y + x1.z*y1.z + x1.w*y1.w;
          a2 += x2.x*y2.x + x2.y*y2.y + x2.z*y2.z + x2.w*y2.w;
          a3 += x3.x*y3.x + x3.y*y3.y + x3.z*y3.z + x3.w*y3.w;
        }
        carr[ci] += (a0 + a1) + (a2 + a3);
      }
    }
#pragma unroll
    for (int ci = 0; ci < 16; ++ci){
      int c = cbase + ci;
      if (c < 1000) l3p[kg*65536 + b*1024 + c] = carr[ci];
    }
  }
}

// =============== K1: GEMM1 + softmax + region partial sums ================
// grid 196 (64 rows each), block 256 (4 waves). B direct from L2 (permuted),
// A through double-buffered swizzled LDS, ONE barrier per K-iteration.
__global__ __launch_bounds__(256, 1) void k1_main(
    const float* __restrict__ am, const u16* __restrict__ w1bp,
    float* __restrict__ partial)
{
  __shared__ __attribute__((aligned(16))) u16 sA[2][64*64];  // 2 x 8 KB swizzled
  __shared__ float redM[64][4];
  __shared__ float redS[64][4];

  const int t = threadIdx.x, w = t >> 6, l = t & 63;
  const int llo = l & 15, lhi = l >> 4;
  const int blk = blockIdx.x;
  const int cb = w * 80;

  const f32x4 zero = {0.f,0.f,0.f,0.f};
  f32x4 acc[4][5];
#pragma unroll
  for (int m = 0; m < 4; ++m)
#pragma unroll
    for (int f = 0; f < 5; ++f) acc[m][f] = zero;

  // A staging: thread -> row ar (0..63), 16 f32 at quarter acq
  const int ar = t >> 2, acq = t & 3;
  const float4* aptr = (const float4*)(am + (size_t)(blk*64 + ar)*2048 + acq*16);
  const int js0 = (acq*2    ) ^ (ar & 7);
  const int js1 = (acq*2 + 1) ^ (ar & 7);
  const int aw0 = ar*64 + js0*8;
  const int aw1 = ar*64 + js1*8;

  // prologue: A(0) -> buf0 ; issue A(1)
  float4 av0 = aptr[0], av1 = aptr[1], av2 = aptr[2], av3 = aptr[3];
  {
    short8 p0, p1;
    p0[0]=(short)f2bf(av0.x); p0[1]=(short)f2bf(av0.y); p0[2]=(short)f2bf(av0.z); p0[3]=(short)f2bf(av0.w);
    p0[4]=(short)f2bf(av1.x); p0[5]=(short)f2bf(av1.y); p0[6]=(short)f2bf(av1.z); p0[7]=(short)f2bf(av1.w);
    p1[0]=(short)f2bf(av2.x); p1[1]=(short)f2bf(av2.y); p1[2]=(short)f2bf(av2.z); p1[3]=(short)f2bf(av2.w);
    p1[4]=(short)f2bf(av3.x); p1[5]=(short)f2bf(av3.y); p1[6]=(short)f2bf(av3.z); p1[7]=(short)f2bf(av3.w);
    *(short8*)(sA[0] + aw0) = p0;
    *(short8*)(sA[0] + aw1) = p1;
  }
  av0 = aptr[16]; av1 = aptr[17]; av2 = aptr[18]; av3 = aptr[19];
  __syncthreads();

  for (int ks = 0; ks < 32; ++ks){
    const int cur = ks & 1;
    // write A(ks+1) into the buffer that was read last iteration
    if (ks < 31){
      short8 p0, p1;
      p0[0]=(short)f2bf(av0.x); p0[1]=(short)f2bf(av0.y); p0[2]=(short)f2bf(av0.z); p0[3]=(short)f2bf(av0.w);
      p0[4]=(short)f2bf(av1.x); p0[5]=(short)f2bf(av1.y); p0[6]=(short)f2bf(av1.z); p0[7]=(short)f2bf(av1.w);
      p1[0]=(short)f2bf(av2.x); p1[1]=(short)f2bf(av2.y); p1[2]=(short)f2bf(av2.z); p1[3]=(short)f2bf(av2.w);
      p1[4]=(short)f2bf(av3.x); p1[5]=(short)f2bf(av3.y); p1[6]=(short)f2bf(av3.z); p1[7]=(short)f2bf(av3.w);
      *(short8*)(sA[cur^1] + aw0) = p0;
      *(short8*)(sA[cur^1] + aw1) = p1;
    }
    // issue A(ks+2) global loads (drained at this iter's barrier)
    if (ks < 30){
      const float4* ap = aptr + (ks+2)*16;
      av0 = ap[0]; av1 = ap[1]; av2 = ap[2]; av3 = ap[3];
    }
    // MFMA over BK=64 (2 k-steps); B fragments straight from L2 (permuted)
#pragma unroll
    for (int kk = 0; kk < 2; ++kk){
      const int jr = ((kk*4 + lhi) ^ (llo & 7)) * 8;
      short8 af[4];
#pragma unroll
      for (int m = 0; m < 4; ++m)
        af[m] = *(const short8*)(sA[cur] + (m*16 + llo)*64 + jr);
      const int kseg = ks*2 + kk;
#pragma unroll
      for (int f = 0; f < 5; ++f){
        short8 bfv = *(const short8*)(w1bp +
            (size_t)(((kseg*20 + w*5 + f)*64 + l)) * 8);
#pragma unroll
        for (int m = 0; m < 4; ++m)
          acc[m][f] = MFMA16(af[m], bfv, acc[m][f]);
      }
    }
    __syncthreads();
  }

  // ---- epilogue: softmax over 320 cols, rows = m*16 + lhi*4 + r ----
  float rmax[4][4];
#pragma unroll
  for (int m = 0; m < 4; ++m)
#pragma unroll
    for (int r = 0; r < 4; ++r){
      float x = acc[m][0][r];
#pragma unroll
      for (int f = 1; f < 5; ++f) x = fmaxf(x, acc[m][f][r]);
      x = fmaxf(x, __shfl_xor(x, 1));
      x = fmaxf(x, __shfl_xor(x, 2));
      x = fmaxf(x, __shfl_xor(x, 4));
      x = fmaxf(x, __shfl_xor(x, 8));
      rmax[m][r] = x;
    }
  if (llo == 0){
#pragma unroll
    for (int m = 0; m < 4; ++m)
#pragma unroll
      for (int r = 0; r < 4; ++r)
        redM[m*16 + lhi*4 + r][w] = rmax[m][r];
  }
  __syncthreads();
#pragma unroll
  for (int m = 0; m < 4; ++m)
#pragma unroll
    for (int r = 0; r < 4; ++r){
      int row = m*16 + lhi*4 + r;
      rmax[m][r] = fmaxf(fmaxf(redM[row][0], redM[row][1]),
                         fmaxf(redM[row][2], redM[row][3]));
    }
  float rsum[4][4];
#pragma unroll
  for (int m = 0; m < 4; ++m)
#pragma unroll
    for (int r = 0; r < 4; ++r){
      float s = 0.f;
#pragma unroll
      for (int f = 0; f < 5; ++f){
        float e = __expf(acc[m][f][r] - rmax[m][r]);
        acc[m][f][r] = e; s += e;
      }
      s += __shfl_xor(s, 1);
      s += __shfl_xor(s, 2);
      s += __shfl_xor(s, 4);
      s += __shfl_xor(s, 8);
      rsum[m][r] = s;
    }
  if (llo == 0){
#pragma unroll
    for (int m = 0; m < 4; ++m)
#pragma unroll
      for (int r = 0; r < 4; ++r)
        redS[m*16 + lhi*4 + r][w] = rsum[m][r];
  }
  __syncthreads();
#pragma unroll
  for (int m = 0; m < 4; ++m)
#pragma unroll
    for (int r = 0; r < 4; ++r){
      int row = m*16 + lhi*4 + r;
      rmax[m][r] = 1.f / (redS[row][0] + redS[row][1] + redS[row][2] + redS[row][3]);
    }
  const int n0 = blk * 64;
  const int thr = 196 * (n0/196 + 1) - n0;     // rows < thr -> seg0
  float s0[5] = {0,0,0,0,0}, s1[5] = {0,0,0,0,0};
#pragma unroll
  for (int m = 0; m < 4; ++m)
#pragma unroll
    for (int r = 0; r < 4; ++r){
      int row = m*16 + lhi*4 + r;
      float sc = rmax[m][r];
      bool in0 = row < thr;
#pragma unroll
      for (int f = 0; f < 5; ++f){
        float v = acc[m][f][r] * sc;
        s0[f] += in0 ? v : 0.f;
        s1[f] += in0 ? 0.f : v;
      }
    }
#pragma unroll
  for (int f = 0; f < 5; ++f){
    s0[f] += __shfl_xor(s0[f], 16); s0[f] += __shfl_xor(s0[f], 32);
    s1[f] += __shfl_xor(s1[f], 16); s1[f] += __shfl_xor(s1[f], 32);
  }
  if (lhi == 0){
#pragma unroll
    for (int f = 0; f < 5; ++f){
      partial[blk*640 +       cb + f*16 + llo] = s0[f];
      partial[blk*640 + 320 + cb + f*16 + llo] = s1[f];
    }
  }
}

// =============== K2c: reduce partials + attr_dis@W2T + both softmax =======
__global__ __launch_bounds__(256) void k2c_final(
    const float* __restrict__ partialp, const float* __restrict__ W2T,
    const float* __restrict__ l3p, float* __restrict__ outp,
    float* __restrict__ out_ad)
{
  __shared__ __attribute__((aligned(16))) float sad[320];
  __shared__ float redA[4], redB[4];
  const int b = blockIdx.x, t = threadIdx.x;
  const int w = t >> 6, l = t & 63;
  // fused k2a: attr_dis for this b
  const int lo = (196*b) >> 6, hi = (196*b + 195) >> 6;
  for (int i = t; i < 320; i += 256){
    float s = 0.f;
    for (int blk = lo; blk <= hi; ++blk){
      int seg = b - (blk*64)/196;
      if (seg >= 0 && seg < 2) s += partialp[blk*640 + seg*320 + i];
    }
    s *= (1.f / 320.f);
    sad[i] = s;
    out_ad[b*320 + i] = s;
  }
  __syncthreads();
  const int c0 = t * 4;
  f32x4 s2v = {0.f,0.f,0.f,0.f};
  const float4* a4 = (const float4*)sad;
#pragma unroll 4
  for (int i = 0; i < 80; ++i){
    float4 sv = a4[i];
    f32x4 w0 = *(const f32x4*)(W2T + (size_t)(4*i  )*1024 + c0);
    f32x4 w1 = *(const f32x4*)(W2T + (size_t)(4*i+1)*1024 + c0);
    f32x4 w2 = *(const f32x4*)(W2T + (size_t)(4*i+2)*1024 + c0);
    f32x4 w3 = *(const f32x4*)(W2T + (size_t)(4*i+3)*1024 + c0);
    s2v += sv.x*w0 + sv.y*w1 + sv.z*w2 + sv.w*w3;
  }
  f32x4 s3v = {0.f,0.f,0.f,0.f};
#pragma unroll
  for (int kg = 0; kg < 8; ++kg)
    s3v += *(const f32x4*)(l3p + kg*65536 + b*1024 + c0);
  float l2a[4], l3a[4];
#pragma unroll
  for (int j = 0; j < 4; ++j){
    bool valid = (c0 + j) < 1000;
    l2a[j] = valid ? s2v[j] : -3.4e38f;
    l3a[j] = valid ? s3v[j] : -3.4e38f;
  }
  float m2 = fmaxf(fmaxf(l2a[0],l2a[1]), fmaxf(l2a[2],l2a[3]));
  float m3 = fmaxf(fmaxf(l3a[0],l3a[1]), fmaxf(l3a[2],l3a[3]));
#pragma unroll
  for (int off = 32; off > 0; off >>= 1){
    m2 = fmaxf(m2, __shfl_xor(m2, off));
    m3 = fmaxf(m3, __shfl_xor(m3, off));
  }
  if (l == 0){ redA[w] = m2; redB[w] = m3; }
  __syncthreads();
  m2 = fmaxf(fmaxf(redA[0],redA[1]), fmaxf(redA[2],redA[3]));
  m3 = fmaxf(fmaxf(redB[0],redB[1]), fmaxf(redB[2],redB[3]));
  __syncthreads();
  float e2[4], e3[4], s2 = 0.f, s3 = 0.f;
#pragma unroll
  for (int j = 0; j < 4; ++j){
    bool valid = (c0 + j) < 1000;
    e2[j] = valid ? __expf(l2a[j] - m2) : 0.f;
    e3[j] = valid ? __expf(l3a[j] - m3) : 0.f;
    s2 += e2[j]; s3 += e3[j];
  }
#pragma unroll
  for (int off = 32; off > 0; off >>= 1){
    s2 += __shfl_xor(s2, off);
    s3 += __shfl_xor(s3, off);
  }
  if (l == 0){ redA[w] = s2; redB[w] = s3; }
  __syncthreads();
  s2 = redA[0] + redA[1] + redA[2] + redA[3];
  s3 = redB[0] + redB[1] + redB[2] + redB[3];
  float i2 = 1.f / s2, i3 = 1.f / s3;
#pragma unroll
  for (int j = 0; j < 4; ++j){
    int c = c0 + j;
    if (c < 1000) outp[b*1000 + c] = 0.5f * (e2[j]*i2 + e3[j]*i3);
  }
}

extern "C" void kernel_launch(void* const* d_in, const int* in_sizes, int n_in,
                              void* d_out, int out_size, void* d_ws, size_t ws_size,
                              hipStream_t stream)
{
  const float* attr_map = (const float*)d_in[0];
  const float* features = (const float*)d_in[1];
  const float* W1 = (const float*)d_in[2];
  const float* W2 = (const float*)d_in[3];
  const float* W3 = (const float*)d_in[4];
  float* outp = (float*)d_out;

  char* ws = (char*)d_ws;
  u16*   w1bp    = (u16*)ws;                       // 1,310,720 B
  float* W2T     = (float*)(ws + 1310720);         // 1,310,720 B
  float* partial = (float*)(ws + 2621440);         //   501,760 B
  float* l3p     = (float*)(ws + 3123200);         // 2,097,152 B  (total 5.2 MB)

  kprep    <<<768, 256, 0, stream>>>(W1, W2, features, W3, w1bp, W2T, l3p);
  k1_main  <<<196, 256, 0, stream>>>(attr_map, w1bp, partial);
  k2c_final<<<64, 256, 0, stream>>>(partial, W2T, l3p, outp, outp + 64000);
}

// Round 5
// 95.055 us; speedup vs baseline: 1.5829x; 1.5829x over previous
//
#include <hip/hip_runtime.h>
#include <hip/hip_bf16.h>

typedef unsigned short u16;
typedef __attribute__((ext_vector_type(8))) short short8;
typedef __attribute__((ext_vector_type(4))) float f32x4;

#define MFMA16(a,b,c) __builtin_amdgcn_mfma_f32_16x16x32_bf16(a,b,c,0,0,0)

__device__ __forceinline__ u16 f2bf(float x){
  union { float f; unsigned u; } v; v.f = x;
  unsigned r = v.u + 0x7FFFu + ((v.u >> 16) & 1u);   // RTNE
  return (u16)(r >> 16);
}

// =============== kPrep: W1-permute + W2 transpose + GEMM3(f32,tiled) ======
// blocks 0..319   : W1[320][2048] f32 -> w1bp bf16 in MFMA-fragment order
// blocks 320..639 : W2[1000][320] -> W2T[320][1024] zero-padded
// blocks 640..895 : l3p[kg(16)][64][1024] = feat @ W3^T split-K partials
__global__ __launch_bounds__(256) void kprep(
    const float* __restrict__ W1, const float* __restrict__ W2,
    const float* __restrict__ feat, const float* __restrict__ W3,
    u16* __restrict__ w1bp, float* __restrict__ W2T, float* __restrict__ l3p)
{
  __shared__ float tile[32][33];
  __shared__ __attribute__((aligned(16))) float At[32*68];
  __shared__ __attribute__((aligned(16))) float Bt[32*68];
  const int bid = blockIdx.x;
  const int t = threadIdx.x;

  if (bid < 320){
    int gid = bid * 256 + t;
    int kseg = gid / 1280;
    int rem = gid - kseg * 1280;
    int f = rem >> 6, l = rem & 63;
    int row = f * 16 + (l & 15);
    int col = kseg * 32 + (l >> 4) * 8;
    const float4* s = (const float4*)(W1 + (size_t)row * 2048 + col);
    float4 a = s[0], b = s[1];
    short8 pk;
    pk[0]=(short)f2bf(a.x); pk[1]=(short)f2bf(a.y); pk[2]=(short)f2bf(a.z); pk[3]=(short)f2bf(a.w);
    pk[4]=(short)f2bf(b.x); pk[5]=(short)f2bf(b.y); pk[6]=(short)f2bf(b.z); pk[7]=(short)f2bf(b.w);
    *(short8*)(w1bp + (size_t)gid * 8) = pk;
  } else if (bid < 640){
    const int bb = bid - 320;
    const int tx = t & 31, ty = t >> 5;          // 32 x 8
    const int bx = bb & 31;                      // c tile (32 -> 1024)
    const int by = bb >> 5;                      // a tile (10 -> 320)
#pragma unroll
    for (int k = 0; k < 4; ++k){
      int c = bx*32 + ty + k*8;
      int a = by*32 + tx;
      tile[ty + k*8][tx] = (c < 1000) ? W2[(size_t)c*320 + a] : 0.f;
    }
    __syncthreads();
#pragma unroll
    for (int k = 0; k < 4; ++k){
      int a = by*32 + ty + k*8;
      int c = bx*32 + tx;
      W2T[(size_t)a*1024 + c] = tile[tx][ty + k*8];
    }
  } else {
    // ---- GEMM3: 64x64 C tile, K chunk 128 (4 stages of 32) ----
    const int bb = bid - 640;
    const int kg = bb & 15;              // K chunk of 128
    const int cg = bb >> 4;              // 16 c-groups of 64
    const int cbase = cg * 64;
    const int tm = t >> 4, tn = t & 15;  // 16x16 threads, 4x4 microtile
    const int sr = t >> 2, skc = (t & 3) * 8;  // staging: row, k-chunk
    f32x4 acc4[4];
#pragma unroll
    for (int i = 0; i < 4; ++i) acc4[i] = (f32x4){0.f,0.f,0.f,0.f};

    for (int st = 0; st < 4; ++st){
      const int kbase = kg*128 + st*32;
      // stage feat[64][32] -> At[k][m] (transposed)
      {
        const float4* s = (const float4*)(feat + (size_t)sr*2048 + kbase + skc);
        float4 v0 = s[0], v1 = s[1];
        At[(skc+0)*68 + sr] = v0.x; At[(skc+1)*68 + sr] = v0.y;
        At[(skc+2)*68 + sr] = v0.z; At[(skc+3)*68 + sr] = v0.w;
        At[(skc+4)*68 + sr] = v1.x; At[(skc+5)*68 + sr] = v1.y;
        At[(skc+6)*68 + sr] = v1.z; At[(skc+7)*68 + sr] = v1.w;
      }
      // stage W3[c 64][32] -> Bt[k][n] (transposed, zero-pad c>=1000)
      {
        int c = cbase + sr;
        float4 v0 = {0,0,0,0}, v1 = {0,0,0,0};
        if (c < 1000){
          const float4* s = (const float4*)(W3 + (size_t)c*2048 + kbase + skc);
          v0 = s[0]; v1 = s[1];
        }
        Bt[(skc+0)*68 + sr] = v0.x; Bt[(skc+1)*68 + sr] = v0.y;
        Bt[(skc+2)*68 + sr] = v0.z; Bt[(skc+3)*68 + sr] = v0.w;
        Bt[(skc+4)*68 + sr] = v1.x; Bt[(skc+5)*68 + sr] = v1.y;
        Bt[(skc+6)*68 + sr] = v1.z; Bt[(skc+7)*68 + sr] = v1.w;
      }
      __syncthreads();
#pragma unroll
      for (int kk = 0; kk < 32; ++kk){
        f32x4 a = *(const f32x4*)(At + kk*68 + tm*4);
        f32x4 b = *(const f32x4*)(Bt + kk*68 + tn*4);
        acc4[0] += a[0] * b;
        acc4[1] += a[1] * b;
        acc4[2] += a[2] * b;
        acc4[3] += a[3] * b;
      }
      __syncthreads();
    }
    // write partials: rows m = tm*4+i (batch), cols c = cbase + tn*4.. (pad ok)
#pragma unroll
    for (int i = 0; i < 4; ++i)
      *(f32x4*)(l3p + (size_t)kg*65536 + (tm*4+i)*1024 + cbase + tn*4) = acc4[i];
  }
}

// =============== K1: GEMM1 + softmax + region partial sums ================
// grid 392 (32 rows each), block 256 (4 waves). B direct from L2 (permuted),
// A through double-buffered swizzled LDS, ONE barrier per K-iteration.
__global__ __launch_bounds__(256, 4) void k1_main(
    const float* __restrict__ am, const u16* __restrict__ w1bp,
    float* __restrict__ partial)
{
  __shared__ __attribute__((aligned(16))) u16 sA[2][32*64];  // 2 x 4 KB swizzled
  __shared__ float redM[32][4];
  __shared__ float redS[32][4];

  const int t = threadIdx.x, w = t >> 6, l = t & 63;
  const int llo = l & 15, lhi = l >> 4;
  const int blk = blockIdx.x;
  const int cb = w * 80;

  f32x4 acc[2][5];
#pragma unroll
  for (int m = 0; m < 2; ++m)
#pragma unroll
    for (int f = 0; f < 5; ++f) acc[m][f] = (f32x4){0.f,0.f,0.f,0.f};

  // A staging: thread -> row ar (0..31), 16B chunk j (0..7) of 64-k slice
  const int ar = t >> 3, j = t & 7;
  const float4* aptr = (const float4*)(am + (size_t)(blk*32 + ar)*2048 + j*8);
  const int aw = ar*64 + (j ^ (ar & 7))*8;

  // prologue: A(0) -> buf0 ; issue A(1)
  float4 av0 = aptr[0], av1 = aptr[1];
  {
    short8 p0;
    p0[0]=(short)f2bf(av0.x); p0[1]=(short)f2bf(av0.y); p0[2]=(short)f2bf(av0.z); p0[3]=(short)f2bf(av0.w);
    p0[4]=(short)f2bf(av1.x); p0[5]=(short)f2bf(av1.y); p0[6]=(short)f2bf(av1.z); p0[7]=(short)f2bf(av1.w);
    *(short8*)(sA[0] + aw) = p0;
  }
  av0 = aptr[16]; av1 = aptr[17];
  __syncthreads();

  for (int ks = 0; ks < 32; ++ks){
    const int cur = ks & 1;
    if (ks < 31){
      short8 p0;
      p0[0]=(short)f2bf(av0.x); p0[1]=(short)f2bf(av0.y); p0[2]=(short)f2bf(av0.z); p0[3]=(short)f2bf(av0.w);
      p0[4]=(short)f2bf(av1.x); p0[5]=(short)f2bf(av1.y); p0[6]=(short)f2bf(av1.z); p0[7]=(short)f2bf(av1.w);
      *(short8*)(sA[cur^1] + aw) = p0;
    }
    if (ks < 30){
      const float4* ap = aptr + (ks+2)*16;
      av0 = ap[0]; av1 = ap[1];
    }
#pragma unroll
    for (int kk = 0; kk < 2; ++kk){
      const int jr = ((kk*4 + lhi) ^ (llo & 7)) * 8;
      short8 af0 = *(const short8*)(sA[cur] + (     llo)*64 + jr);
      short8 af1 = *(const short8*)(sA[cur] + (16 + llo)*64 + jr);
      const int kseg = ks*2 + kk;
#pragma unroll
      for (int f = 0; f < 5; ++f){
        short8 bfv = *(const short8*)(w1bp +
            (size_t)(((kseg*20 + w*5 + f)*64 + l)) * 8);
        acc[0][f] = MFMA16(af0, bfv, acc[0][f]);
        acc[1][f] = MFMA16(af1, bfv, acc[1][f]);
      }
    }
    __syncthreads();
  }

  // ---- epilogue: softmax over 320 cols, rows = m*16 + lhi*4 + r ----
  float rmax[2][4];
#pragma unroll
  for (int m = 0; m < 2; ++m)
#pragma unroll
    for (int r = 0; r < 4; ++r){
      float x = acc[m][0][r];
#pragma unroll
      for (int f = 1; f < 5; ++f) x = fmaxf(x, acc[m][f][r]);
      x = fmaxf(x, __shfl_xor(x, 1));
      x = fmaxf(x, __shfl_xor(x, 2));
      x = fmaxf(x, __shfl_xor(x, 4));
      x = fmaxf(x, __shfl_xor(x, 8));
      rmax[m][r] = x;
    }
  if (llo == 0){
#pragma unroll
    for (int m = 0; m < 2; ++m)
#pragma unroll
      for (int r = 0; r < 4; ++r)
        redM[m*16 + lhi*4 + r][w] = rmax[m][r];
  }
  __syncthreads();
#pragma unroll
  for (int m = 0; m < 2; ++m)
#pragma unroll
    for (int r = 0; r < 4; ++r){
      int row = m*16 + lhi*4 + r;
      rmax[m][r] = fmaxf(fmaxf(redM[row][0], redM[row][1]),
                         fmaxf(redM[row][2], redM[row][3]));
    }
  float rsum[2][4];
#pragma unroll
  for (int m = 0; m < 2; ++m)
#pragma unroll
    for (int r = 0; r < 4; ++r){
      float s = 0.f;
#pragma unroll
      for (int f = 0; f < 5; ++f){
        float e = __expf(acc[m][f][r] - rmax[m][r]);
        acc[m][f][r] = e; s += e;
      }
      s += __shfl_xor(s, 1);
      s += __shfl_xor(s, 2);
      s += __shfl_xor(s, 4);
      s += __shfl_xor(s, 8);
      rsum[m][r] = s;
    }
  if (llo == 0){
#pragma unroll
    for (int m = 0; m < 2; ++m)
#pragma unroll
      for (int r = 0; r < 4; ++r)
        redS[m*16 + lhi*4 + r][w] = rsum[m][r];
  }
  __syncthreads();
#pragma unroll
  for (int m = 0; m < 2; ++m)
#pragma unroll
    for (int r = 0; r < 4; ++r){
      int row = m*16 + lhi*4 + r;
      rmax[m][r] = 1.f / (redS[row][0] + redS[row][1] + redS[row][2] + redS[row][3]);
    }
  const int n0 = blk * 32;
  const int thr = 196 * (n0/196 + 1) - n0;     // rows < thr -> seg0
  float s0[5] = {0,0,0,0,0}, s1[5] = {0,0,0,0,0};
#pragma unroll
  for (int m = 0; m < 2; ++m)
#pragma unroll
    for (int r = 0; r < 4; ++r){
      int row = m*16 + lhi*4 + r;
      float sc = rmax[m][r];
      bool in0 = row < thr;
#pragma unroll
      for (int f = 0; f < 5; ++f){
        float v = acc[m][f][r] * sc;
        s0[f] += in0 ? v : 0.f;
        s1[f] += in0 ? 0.f : v;
      }
    }
#pragma unroll
  for (int f = 0; f < 5; ++f){
    s0[f] += __shfl_xor(s0[f], 16); s0[f] += __shfl_xor(s0[f], 32);
    s1[f] += __shfl_xor(s1[f], 16); s1[f] += __shfl_xor(s1[f], 32);
  }
  if (lhi == 0){
#pragma unroll
    for (int f = 0; f < 5; ++f){
      partial[blk*640 +       cb + f*16 + llo] = s0[f];
      partial[blk*640 + 320 + cb + f*16 + llo] = s1[f];
    }
  }
}

// =============== K2c: reduce partials + attr_dis@W2T + both softmax =======
__global__ __launch_bounds__(256) void k2c_final(
    const float* __restrict__ partialp, const float* __restrict__ W2T,
    const float* __restrict__ l3p, float* __restrict__ outp,
    float* __restrict__ out_ad)
{
  __shared__ __attribute__((aligned(16))) float sad[320];
  __shared__ float redA[4], redB[4];
  const int b = blockIdx.x, t = threadIdx.x;
  const int w = t >> 6, l = t & 63;
  const int lo = (196*b) >> 5, hi = (196*b + 195) >> 5;
  for (int i = t; i < 320; i += 256){
    float s = 0.f;
    for (int blk = lo; blk <= hi; ++blk){
      int seg = b - (blk*32)/196;
      if (seg >= 0 && seg < 2) s += partialp[blk*640 + seg*320 + i];
    }
    s *= (1.f / 320.f);
    sad[i] = s;
    out_ad[b*320 + i] = s;
  }
  __syncthreads();
  const int c0 = t * 4;
  f32x4 s2v = {0.f,0.f,0.f,0.f};
  const float4* a4 = (const float4*)sad;
#pragma unroll 4
  for (int i = 0; i < 80; ++i){
    float4 sv = a4[i];
    f32x4 w0 = *(const f32x4*)(W2T + (size_t)(4*i  )*1024 + c0);
    f32x4 w1 = *(const f32x4*)(W2T + (size_t)(4*i+1)*1024 + c0);
    f32x4 w2 = *(const f32x4*)(W2T + (size_t)(4*i+2)*1024 + c0);
    f32x4 w3 = *(const f32x4*)(W2T + (size_t)(4*i+3)*1024 + c0);
    s2v += sv.x*w0 + sv.y*w1 + sv.z*w2 + sv.w*w3;
  }
  f32x4 s3v = {0.f,0.f,0.f,0.f};
#pragma unroll
  for (int kg = 0; kg < 16; ++kg)
    s3v += *(const f32x4*)(l3p + (size_t)kg*65536 + b*1024 + c0);
  float l2a[4], l3a[4];
#pragma unroll
  for (int j = 0; j < 4; ++j){
    bool valid = (c0 + j) < 1000;
    l2a[j] = valid ? s2v[j] : -3.4e38f;
    l3a[j] = valid ? s3v[j] : -3.4e38f;
  }
  float m2 = fmaxf(fmaxf(l2a[0],l2a[1]), fmaxf(l2a[2],l2a[3]));
  float m3 = fmaxf(fmaxf(l3a[0],l3a[1]), fmaxf(l3a[2],l3a[3]));
#pragma unroll
  for (int off = 32; off > 0; off >>= 1){
    m2 = fmaxf(m2, __shfl_xor(m2, off));
    m3 = fmaxf(m3, __shfl_xor(m3, off));
  }
  if (l == 0){ redA[w] = m2; redB[w] = m3; }
  __syncthreads();
  m2 = fmaxf(fmaxf(redA[0],redA[1]), fmaxf(redA[2],redA[3]));
  m3 = fmaxf(fmaxf(redB[0],redB[1]), fmaxf(redB[2],redB[3]));
  __syncthreads();
  float e2[4], e3[4], s2 = 0.f, s3 = 0.f;
#pragma unroll
  for (int j = 0; j < 4; ++j){
    bool valid = (c0 + j) < 1000;
    e2[j] = valid ? __expf(l2a[j] - m2) : 0.f;
    e3[j] = valid ? __expf(l3a[j] - m3) : 0.f;
    s2 += e2[j]; s3 += e3[j];
  }
#pragma unroll
  for (int off = 32; off > 0; off >>= 1){
    s2 += __shfl_xor(s2, off);
    s3 += __shfl_xor(s3, off);
  }
  if (l == 0){ redA[w] = s2; redB[w] = s3; }
  __syncthreads();
  s2 = redA[0] + redA[1] + redA[2] + redA[3];
  s3 = redB[0] + redB[1] + redB[2] + redB[3];
  float i2 = 1.f / s2, i3 = 1.f / s3;
#pragma unroll
  for (int j = 0; j < 4; ++j){
    int c = c0 + j;
    if (c < 1000) outp[b*1000 + c] = 0.5f * (e2[j]*i2 + e3[j]*i3);
  }
}

extern "C" void kernel_launch(void* const* d_in, const int* in_sizes, int n_in,
                              void* d_out, int out_size, void* d_ws, size_t ws_size,
                              hipStream_t stream)
{
  const float* attr_map = (const float*)d_in[0];
  const float* features = (const float*)d_in[1];
  const float* W1 = (const float*)d_in[2];
  const float* W2 = (const float*)d_in[3];
  const float* W3 = (const float*)d_in[4];
  float* outp = (float*)d_out;

  char* ws = (char*)d_ws;
  u16*   w1bp    = (u16*)ws;                       // 1,310,720 B
  float* W2T     = (float*)(ws + 1310720);         // 1,310,720 B
  float* partial = (float*)(ws + 2621440);         // 1,003,520 B
  float* l3p     = (float*)(ws + 3624960);         // 4,194,304 B (total 7.8 MB)

  kprep    <<<896, 256, 0, stream>>>(W1, W2, features, W3, w1bp, W2T, l3p);
  k1_main  <<<392, 256, 0, stream>>>(attr_map, w1bp, partial);
  k2c_final<<<64, 256, 0, stream>>>(partial, W2T, l3p, outp, outp + 64000);
}

// Round 6
// 93.734 us; speedup vs baseline: 1.6053x; 1.0141x over previous
//
#include <hip/hip_runtime.h>
#include <hip/hip_bf16.h>

typedef unsigned short u16;
typedef __attribute__((ext_vector_type(8))) short short8;
typedef __attribute__((ext_vector_type(4))) float f32x4;

#define MFMA16(a,b,c) __builtin_amdgcn_mfma_f32_16x16x32_bf16(a,b,c,0,0,0)
#define LGKM_BARRIER() asm volatile("s_waitcnt lgkmcnt(0)\n\ts_barrier" ::: "memory")

__device__ __forceinline__ u16 f2bf(float x){
  union { float f; unsigned u; } v; v.f = x;
  unsigned r = v.u + 0x7FFFu + ((v.u >> 16) & 1u);   // RTNE
  return (u16)(r >> 16);
}

__device__ __forceinline__ short8 pack8(float4 a, float4 b){
  short8 p;
  p[0]=(short)f2bf(a.x); p[1]=(short)f2bf(a.y); p[2]=(short)f2bf(a.z); p[3]=(short)f2bf(a.w);
  p[4]=(short)f2bf(b.x); p[5]=(short)f2bf(b.y); p[6]=(short)f2bf(b.z); p[7]=(short)f2bf(b.w);
  return p;
}

// =============== kPrep: W1-permute + W2 transpose + GEMM3(f32,tiled) ======
// blocks 0..319   : W1[320][2048] f32 -> w1bp bf16 in MFMA-fragment order
// blocks 320..639 : W2[1000][320] -> W2T[320][1024] zero-padded
// blocks 640..895 : l3p[kg(16)][64][1024] = feat @ W3^T split-K partials
__global__ __launch_bounds__(256) void kprep(
    const float* __restrict__ W1, const float* __restrict__ W2,
    const float* __restrict__ feat, const float* __restrict__ W3,
    u16* __restrict__ w1bp, float* __restrict__ W2T, float* __restrict__ l3p)
{
  __shared__ float tile[32][33];
  __shared__ __attribute__((aligned(16))) float At[32*68];
  __shared__ __attribute__((aligned(16))) float Bt[32*68];
  const int bid = blockIdx.x;
  const int t = threadIdx.x;

  if (bid < 320){
    int gid = bid * 256 + t;
    int kseg = gid / 1280;
    int rem = gid - kseg * 1280;
    int f = rem >> 6, l = rem & 63;
    int row = f * 16 + (l & 15);
    int col = kseg * 32 + (l >> 4) * 8;
    const float4* s = (const float4*)(W1 + (size_t)row * 2048 + col);
    float4 a = s[0], b = s[1];
    *(short8*)(w1bp + (size_t)gid * 8) = pack8(a, b);
  } else if (bid < 640){
    const int bb = bid - 320;
    const int tx = t & 31, ty = t >> 5;          // 32 x 8
    const int bx = bb & 31;                      // c tile (32 -> 1024)
    const int by = bb >> 5;                      // a tile (10 -> 320)
#pragma unroll
    for (int k = 0; k < 4; ++k){
      int c = bx*32 + ty + k*8;
      int a = by*32 + tx;
      tile[ty + k*8][tx] = (c < 1000) ? W2[(size_t)c*320 + a] : 0.f;
    }
    __syncthreads();
#pragma unroll
    for (int k = 0; k < 4; ++k){
      int a = by*32 + ty + k*8;
      int c = bx*32 + tx;
      W2T[(size_t)a*1024 + c] = tile[tx][ty + k*8];
    }
  } else {
    // ---- GEMM3: 64x64 C tile, K chunk 128 (4 stages of 32) ----
    const int bb = bid - 640;
    const int kg = bb & 15;              // K chunk of 128
    const int cg = bb >> 4;              // 16 c-groups of 64
    const int cbase = cg * 64;
    const int tm = t >> 4, tn = t & 15;  // 16x16 threads, 4x4 microtile
    const int sr = t >> 2, skc = (t & 3) * 8;  // staging: row, k-chunk
    f32x4 acc4[4];
#pragma unroll
    for (int i = 0; i < 4; ++i) acc4[i] = (f32x4){0.f,0.f,0.f,0.f};

    for (int st = 0; st < 4; ++st){
      const int kbase = kg*128 + st*32;
      {
        const float4* s = (const float4*)(feat + (size_t)sr*2048 + kbase + skc);
        float4 v0 = s[0], v1 = s[1];
        At[(skc+0)*68 + sr] = v0.x; At[(skc+1)*68 + sr] = v0.y;
        At[(skc+2)*68 + sr] = v0.z; At[(skc+3)*68 + sr] = v0.w;
        At[(skc+4)*68 + sr] = v1.x; At[(skc+5)*68 + sr] = v1.y;
        At[(skc+6)*68 + sr] = v1.z; At[(skc+7)*68 + sr] = v1.w;
      }
      {
        int c = cbase + sr;
        float4 v0 = {0,0,0,0}, v1 = {0,0,0,0};
        if (c < 1000){
          const float4* s = (const float4*)(W3 + (size_t)c*2048 + kbase + skc);
          v0 = s[0]; v1 = s[1];
        }
        Bt[(skc+0)*68 + sr] = v0.x; Bt[(skc+1)*68 + sr] = v0.y;
        Bt[(skc+2)*68 + sr] = v0.z; Bt[(skc+3)*68 + sr] = v0.w;
        Bt[(skc+4)*68 + sr] = v1.x; Bt[(skc+5)*68 + sr] = v1.y;
        Bt[(skc+6)*68 + sr] = v1.z; Bt[(skc+7)*68 + sr] = v1.w;
      }
      __syncthreads();
#pragma unroll
      for (int kk = 0; kk < 32; ++kk){
        f32x4 a = *(const f32x4*)(At + kk*68 + tm*4);
        f32x4 b = *(const f32x4*)(Bt + kk*68 + tn*4);
        acc4[0] += a[0] * b;
        acc4[1] += a[1] * b;
        acc4[2] += a[2] * b;
        acc4[3] += a[3] * b;
      }
      __syncthreads();
    }
#pragma unroll
    for (int i = 0; i < 4; ++i)
      *(f32x4*)(l3p + (size_t)kg*65536 + (tm*4+i)*1024 + cbase + tn*4) = acc4[i];
  }
}

// =============== K1: GEMM1 + softmax + region partial sums ================
// grid 392 (32 rows each), block 256 (4 waves). B from L2 (permuted frags),
// A through dbuf swizzled LDS. lgkmcnt-only barrier; loads pipelined:
// per iter: [stw A(ks+1)] [B regs] [issue A(ks+3)] [MFMA] [lgkm barrier].
__global__ __launch_bounds__(256, 2) void k1_main(
    const float* __restrict__ am, const u16* __restrict__ w1bp,
    float* __restrict__ partial)
{
  __shared__ __attribute__((aligned(16))) u16 sAbuf[2][32*64];  // 2 x 4 KB swizzled
  __shared__ float redM[32][4];
  __shared__ float redS[32][4];
  u16* const s0 = &sAbuf[0][0];
  u16* const s1 = &sAbuf[1][0];

  const int t = threadIdx.x, w = t >> 6, l = t & 63;
  const int llo = l & 15, lhi = l >> 4;
  const int blk = blockIdx.x;
  const int cb = w * 80;

  f32x4 acc[2][5];
#pragma unroll
  for (int m = 0; m < 2; ++m)
#pragma unroll
    for (int f = 0; f < 5; ++f) acc[m][f] = (f32x4){0.f,0.f,0.f,0.f};

  // A staging: thread -> row ar (0..31), 16B chunk j (0..7) of 64-k slice
  const int ar = t >> 3, j = t & 7;
  const float4* aptr = (const float4*)(am + (size_t)(blk*32 + ar)*2048 + j*8);
  const int aw = ar*64 + (j ^ (ar & 7))*8;

  // B fragment base for this wave/lane
  const u16* const bbase = w1bp + (size_t)(w*5)*512 + (size_t)l*8;

  float4 e0, e1, o0, o1;          // even / odd A-tile register sets
  // prologue: A(0)->s0 ; issue A(1) (odd), A(2) (even)
  e0 = aptr[0]; e1 = aptr[1];
  *(short8*)(s0 + aw) = pack8(e0, e1);
  o0 = aptr[16]; o1 = aptr[17];
  e0 = aptr[32]; e1 = aptr[33];
  LGKM_BARRIER();

  for (int ks2 = 0; ks2 < 16; ++ks2){
    // ---------- even sub-iter: ks = 2*ks2, compute from s0 ----------
    {
      const int ks = 2*ks2;
      *(short8*)(s1 + aw) = pack8(o0, o1);            // A(ks+1), waits its vmcnt
      const u16* bp = bbase + (size_t)(2*ks)*10240;   // kseg = 2ks (20*512)
      short8 bv0[5], bv1[5];
#pragma unroll
      for (int f = 0; f < 5; ++f) bv0[f] = *(const short8*)(bp + (size_t)f*512);
#pragma unroll
      for (int f = 0; f < 5; ++f) bv1[f] = *(const short8*)(bp + (size_t)(20+f)*512);
      if (ks2 < 15){                                  // issue A(ks+3) (odd)
        o0 = aptr[(ks+3)*16]; o1 = aptr[(ks+3)*16 + 1];
      }
#pragma unroll
      for (int kk = 0; kk < 2; ++kk){
        const int jr = ((kk*4 + lhi) ^ (llo & 7)) * 8;
        short8 af0 = *(const short8*)(s0 + llo*64 + jr);
        short8 af1 = *(const short8*)(s0 + (16 + llo)*64 + jr);
#pragma unroll
        for (int f = 0; f < 5; ++f){
          short8 bb = kk ? bv1[f] : bv0[f];
          acc[0][f] = MFMA16(af0, bb, acc[0][f]);
          acc[1][f] = MFMA16(af1, bb, acc[1][f]);
        }
      }
      LGKM_BARRIER();
    }
    // ---------- odd sub-iter: ks = 2*ks2+1, compute from s1 ----------
    {
      const int ks = 2*ks2 + 1;
      if (ks2 < 15)
        *(short8*)(s0 + aw) = pack8(e0, e1);          // A(ks+1) (even)
      const u16* bp = bbase + (size_t)(2*ks)*10240;
      short8 bv0[5], bv1[5];
#pragma unroll
      for (int f = 0; f < 5; ++f) bv0[f] = *(const short8*)(bp + (size_t)f*512);
#pragma unroll
      for (int f = 0; f < 5; ++f) bv1[f] = *(const short8*)(bp + (size_t)(20+f)*512);
      if (ks2 < 14){                                  // issue A(ks+3) (even)
        e0 = aptr[(ks+3)*16]; e1 = aptr[(ks+3)*16 + 1];
      }
#pragma unroll
      for (int kk = 0; kk < 2; ++kk){
        const int jr = ((kk*4 + lhi) ^ (llo & 7)) * 8;
        short8 af0 = *(const short8*)(s1 + llo*64 + jr);
        short8 af1 = *(const short8*)(s1 + (16 + llo)*64 + jr);
#pragma unroll
        for (int f = 0; f < 5; ++f){
          short8 bb = kk ? bv1[f] : bv0[f];
          acc[0][f] = MFMA16(af0, bb, acc[0][f]);
          acc[1][f] = MFMA16(af1, bb, acc[1][f]);
        }
      }
      LGKM_BARRIER();
    }
  }

  // ---- epilogue: softmax over 320 cols, rows = m*16 + lhi*4 + r ----
  float rmax[2][4];
#pragma unroll
  for (int m = 0; m < 2; ++m)
#pragma unroll
    for (int r = 0; r < 4; ++r){
      float x = acc[m][0][r];
#pragma unroll
      for (int f = 1; f < 5; ++f) x = fmaxf(x, acc[m][f][r]);
      x = fmaxf(x, __shfl_xor(x, 1));
      x = fmaxf(x, __shfl_xor(x, 2));
      x = fmaxf(x, __shfl_xor(x, 4));
      x = fmaxf(x, __shfl_xor(x, 8));
      rmax[m][r] = x;
    }
  if (llo == 0){
#pragma unroll
    for (int m = 0; m < 2; ++m)
#pragma unroll
      for (int r = 0; r < 4; ++r)
        redM[m*16 + lhi*4 + r][w] = rmax[m][r];
  }
  __syncthreads();
#pragma unroll
  for (int m = 0; m < 2; ++m)
#pragma unroll
    for (int r = 0; r < 4; ++r){
      int row = m*16 + lhi*4 + r;
      rmax[m][r] = fmaxf(fmaxf(redM[row][0], redM[row][1]),
                         fmaxf(redM[row][2], redM[row][3]));
    }
  float rsum[2][4];
#pragma unroll
  for (int m = 0; m < 2; ++m)
#pragma unroll
    for (int r = 0; r < 4; ++r){
      float s = 0.f;
#pragma unroll
      for (int f = 0; f < 5; ++f){
        float e = __expf(acc[m][f][r] - rmax[m][r]);
        acc[m][f][r] = e; s += e;
      }
      s += __shfl_xor(s, 1);
      s += __shfl_xor(s, 2);
      s += __shfl_xor(s, 4);
      s += __shfl_xor(s, 8);
      rsum[m][r] = s;
    }
  if (llo == 0){
#pragma unroll
    for (int m = 0; m < 2; ++m)
#pragma unroll
      for (int r = 0; r < 4; ++r)
        redS[m*16 + lhi*4 + r][w] = rsum[m][r];
  }
  __syncthreads();
#pragma unroll
  for (int m = 0; m < 2; ++m)
#pragma unroll
    for (int r = 0; r < 4; ++r){
      int row = m*16 + lhi*4 + r;
      rmax[m][r] = 1.f / (redS[row][0] + redS[row][1] + redS[row][2] + redS[row][3]);
    }
  const int n0 = blk * 32;
  const int thr = 196 * (n0/196 + 1) - n0;     // rows < thr -> seg0
  float sseg0[5] = {0,0,0,0,0}, sseg1[5] = {0,0,0,0,0};
#pragma unroll
  for (int m = 0; m < 2; ++m)
#pragma unroll
    for (int r = 0; r < 4; ++r){
      int row = m*16 + lhi*4 + r;
      float sc = rmax[m][r];
      bool in0 = row < thr;
#pragma unroll
      for (int f = 0; f < 5; ++f){
        float v = acc[m][f][r] * sc;
        sseg0[f] += in0 ? v : 0.f;
        sseg1[f] += in0 ? 0.f : v;
      }
    }
#pragma unroll
  for (int f = 0; f < 5; ++f){
    sseg0[f] += __shfl_xor(sseg0[f], 16); sseg0[f] += __shfl_xor(sseg0[f], 32);
    sseg1[f] += __shfl_xor(sseg1[f], 16); sseg1[f] += __shfl_xor(sseg1[f], 32);
  }
  if (lhi == 0){
#pragma unroll
    for (int f = 0; f < 5; ++f){
      partial[blk*640 +       cb + f*16 + llo] = sseg0[f];
      partial[blk*640 + 320 + cb + f*16 + llo] = sseg1[f];
    }
  }
}

// =============== K2c: reduce partials + attr_dis@W2T + both softmax =======
__global__ __launch_bounds__(256) void k2c_final(
    const float* __restrict__ partialp, const float* __restrict__ W2T,
    const float* __restrict__ l3p, float* __restrict__ outp,
    float* __restrict__ out_ad)
{
  __shared__ __attribute__((aligned(16))) float sad[320];
  __shared__ float redA[4], redB[4];
  const int b = blockIdx.x, t = threadIdx.x;
  const int w = t >> 6, l = t & 63;
  const int lo = (196*b) >> 5, hi = (196*b + 195) >> 5;
  for (int i = t; i < 320; i += 256){
    float s = 0.f;
    for (int blk = lo; blk <= hi; ++blk){
      int seg = b - (blk*32)/196;
      if (seg >= 0 && seg < 2) s += partialp[blk*640 + seg*320 + i];
    }
    s *= (1.f / 320.f);
    sad[i] = s;
    out_ad[b*320 + i] = s;
  }
  __syncthreads();
  const int c0 = t * 4;
  f32x4 s2v = {0.f,0.f,0.f,0.f};
  const float4* a4 = (const float4*)sad;
#pragma unroll 4
  for (int i = 0; i < 80; ++i){
    float4 sv = a4[i];
    f32x4 w0 = *(const f32x4*)(W2T + (size_t)(4*i  )*1024 + c0);
    f32x4 w1 = *(const f32x4*)(W2T + (size_t)(4*i+1)*1024 + c0);
    f32x4 w2 = *(const f32x4*)(W2T + (size_t)(4*i+2)*1024 + c0);
    f32x4 w3 = *(const f32x4*)(W2T + (size_t)(4*i+3)*1024 + c0);
    s2v += sv.x*w0 + sv.y*w1 + sv.z*w2 + sv.w*w3;
  }
  f32x4 s3v = {0.f,0.f,0.f,0.f};
#pragma unroll
  for (int kg = 0; kg < 16; ++kg)
    s3v += *(const f32x4*)(l3p + (size_t)kg*65536 + b*1024 + c0);
  float l2a[4], l3a[4];
#pragma unroll
  for (int jj = 0; jj < 4; ++jj){
    bool valid = (c0 + jj) < 1000;
    l2a[jj] = valid ? s2v[jj] : -3.4e38f;
    l3a[jj] = valid ? s3v[jj] : -3.4e38f;
  }
  float m2 = fmaxf(fmaxf(l2a[0],l2a[1]), fmaxf(l2a[2],l2a[3]));
  float m3 = fmaxf(fmaxf(l3a[0],l3a[1]), fmaxf(l3a[2],l3a[3]));
#pragma unroll
  for (int off = 32; off > 0; off >>= 1){
    m2 = fmaxf(m2, __shfl_xor(m2, off));
    m3 = fmaxf(m3, __shfl_xor(m3, off));
  }
  if (l == 0){ redA[w] = m2; redB[w] = m3; }
  __syncthreads();
  m2 = fmaxf(fmaxf(redA[0],redA[1]), fmaxf(redA[2],redA[3]));
  m3 = fmaxf(fmaxf(redB[0],redB[1]), fmaxf(redB[2],redB[3]));
  __syncthreads();
  float e2[4], e3[4], s2 = 0.f, s3 = 0.f;
#pragma unroll
  for (int jj = 0; jj < 4; ++jj){
    bool valid = (c0 + jj) < 1000;
    e2[jj] = valid ? __expf(l2a[jj] - m2) : 0.f;
    e3[jj] = valid ? __expf(l3a[jj] - m3) : 0.f;
    s2 += e2[jj]; s3 += e3[jj];
  }
#pragma unroll
  for (int off = 32; off > 0; off >>= 1){
    s2 += __shfl_xor(s2, off);
    s3 += __shfl_xor(s3, off);
  }
  if (l == 0){ redA[w] = s2; redB[w] = s3; }
  __syncthreads();
  s2 = redA[0] + redA[1] + redA[2] + redA[3];
  s3 = redB[0] + redB[1] + redB[2] + redB[3];
  float i2 = 1.f / s2, i3 = 1.f / s3;
#pragma unroll
  for (int jj = 0; jj < 4; ++jj){
    int c = c0 + jj;
    if (c < 1000) outp[b*1000 + c] = 0.5f * (e2[jj]*i2 + e3[jj]*i3);
  }
}

extern "C" void kernel_launch(void* const* d_in, const int* in_sizes, int n_in,
                              void* d_out, int out_size, void* d_ws, size_t ws_size,
                              hipStream_t stream)
{
  const float* attr_map = (const float*)d_in[0];
  const float* features = (const float*)d_in[1];
  const float* W1 = (const float*)d_in[2];
  const float* W2 = (const float*)d_in[3];
  const float* W3 = (const float*)d_in[4];
  float* outp = (float*)d_out;

  char* ws = (char*)d_ws;
  u16*   w1bp    = (u16*)ws;                       // 1,310,720 B
  float* W2T     = (float*)(ws + 1310720);         // 1,310,720 B
  float* partial = (float*)(ws + 2621440);         // 1,003,520 B
  float* l3p     = (float*)(ws + 3624960);         // 4,194,304 B (total 7.8 MB)

  kprep    <<<896, 256, 0, stream>>>(W1, W2, features, W3, w1bp, W2T, l3p);
  k1_main  <<<392, 256, 0, stream>>>(attr_map, w1bp, partial);
  k2c_final<<<64, 256, 0, stream>>>(partial, W2T, l3p, outp, outp + 64000);
}

// Round 7
// 81.689 us; speedup vs baseline: 1.8420x; 1.1474x over previous
//
#include <hip/hip_runtime.h>
#include <hip/hip_bf16.h>

typedef unsigned short u16;
typedef __attribute__((ext_vector_type(8))) short short8;
typedef __attribute__((ext_vector_type(4))) float f32x4;

#define MFMA16(a,b,c) __builtin_amdgcn_mfma_f32_16x16x32_bf16(a,b,c,0,0,0)
#define LGKM_BARRIER() asm volatile("s_waitcnt lgkmcnt(0)\n\ts_barrier" ::: "memory")
#define SB0() __builtin_amdgcn_sched_barrier(0)

__device__ __forceinline__ u16 f2bf(float x){
  union { float f; unsigned u; } v; v.f = x;
  unsigned r = v.u + 0x7FFFu + ((v.u >> 16) & 1u);   // RTNE
  return (u16)(r >> 16);
}

__device__ __forceinline__ short8 pack8(float4 a, float4 b){
  short8 p;
  p[0]=(short)f2bf(a.x); p[1]=(short)f2bf(a.y); p[2]=(short)f2bf(a.z); p[3]=(short)f2bf(a.w);
  p[4]=(short)f2bf(b.x); p[5]=(short)f2bf(b.y); p[6]=(short)f2bf(b.z); p[7]=(short)f2bf(b.w);
  return p;
}

// =============== kPrep: W1-permute + W2 transpose + GEMM3(f32,tiled) ======
__global__ __launch_bounds__(256) void kprep(
    const float* __restrict__ W1, const float* __restrict__ W2,
    const float* __restrict__ feat, const float* __restrict__ W3,
    u16* __restrict__ w1bp, float* __restrict__ W2T, float* __restrict__ l3p)
{
  __shared__ float tile[32][33];
  __shared__ __attribute__((aligned(16))) float At[32*68];
  __shared__ __attribute__((aligned(16))) float Bt[32*68];
  const int bid = blockIdx.x;
  const int t = threadIdx.x;

  if (bid < 320){
    int gid = bid * 256 + t;
    int kseg = gid / 1280;
    int rem = gid - kseg * 1280;
    int f = rem >> 6, l = rem & 63;
    int row = f * 16 + (l & 15);
    int col = kseg * 32 + (l >> 4) * 8;
    const float4* s = (const float4*)(W1 + (size_t)row * 2048 + col);
    float4 a = s[0], b = s[1];
    *(short8*)(w1bp + (size_t)gid * 8) = pack8(a, b);
  } else if (bid < 640){
    const int bb = bid - 320;
    const int tx = t & 31, ty = t >> 5;          // 32 x 8
    const int bx = bb & 31;                      // c tile (32 -> 1024)
    const int by = bb >> 5;                      // a tile (10 -> 320)
#pragma unroll
    for (int k = 0; k < 4; ++k){
      int c = bx*32 + ty + k*8;
      int a = by*32 + tx;
      tile[ty + k*8][tx] = (c < 1000) ? W2[(size_t)c*320 + a] : 0.f;
    }
    __syncthreads();
#pragma unroll
    for (int k = 0; k < 4; ++k){
      int a = by*32 + ty + k*8;
      int c = bx*32 + tx;
      W2T[(size_t)a*1024 + c] = tile[tx][ty + k*8];
    }
  } else {
    // ---- GEMM3: 64x64 C tile, K chunk 128 (4 stages of 32) ----
    const int bb = bid - 640;
    const int kg = bb & 15;              // K chunk of 128
    const int cg = bb >> 4;              // 16 c-groups of 64
    const int cbase = cg * 64;
    const int tm = t >> 4, tn = t & 15;  // 16x16 threads, 4x4 microtile
    const int sr = t >> 2, skc = (t & 3) * 8;  // staging: row, k-chunk
    f32x4 acc4[4];
#pragma unroll
    for (int i = 0; i < 4; ++i) acc4[i] = (f32x4){0.f,0.f,0.f,0.f};

    for (int st = 0; st < 4; ++st){
      const int kbase = kg*128 + st*32;
      {
        const float4* s = (const float4*)(feat + (size_t)sr*2048 + kbase + skc);
        float4 v0 = s[0], v1 = s[1];
        At[(skc+0)*68 + sr] = v0.x; At[(skc+1)*68 + sr] = v0.y;
        At[(skc+2)*68 + sr] = v0.z; At[(skc+3)*68 + sr] = v0.w;
        At[(skc+4)*68 + sr] = v1.x; At[(skc+5)*68 + sr] = v1.y;
        At[(skc+6)*68 + sr] = v1.z; At[(skc+7)*68 + sr] = v1.w;
      }
      {
        int c = cbase + sr;
        float4 v0 = {0,0,0,0}, v1 = {0,0,0,0};
        if (c < 1000){
          const float4* s = (const float4*)(W3 + (size_t)c*2048 + kbase + skc);
          v0 = s[0]; v1 = s[1];
        }
        Bt[(skc+0)*68 + sr] = v0.x; Bt[(skc+1)*68 + sr] = v0.y;
        Bt[(skc+2)*68 + sr] = v0.z; Bt[(skc+3)*68 + sr] = v0.w;
        Bt[(skc+4)*68 + sr] = v1.x; Bt[(skc+5)*68 + sr] = v1.y;
        Bt[(skc+6)*68 + sr] = v1.z; Bt[(skc+7)*68 + sr] = v1.w;
      }
      __syncthreads();
#pragma unroll
      for (int kk = 0; kk < 32; ++kk){
        f32x4 a = *(const f32x4*)(At + kk*68 + tm*4);
        f32x4 b = *(const f32x4*)(Bt + kk*68 + tn*4);
        acc4[0] += a[0] * b;
        acc4[1] += a[1] * b;
        acc4[2] += a[2] * b;
        acc4[3] += a[3] * b;
      }
      __syncthreads();
    }
#pragma unroll
    for (int i = 0; i < 4; ++i)
      *(f32x4*)(l3p + (size_t)kg*65536 + (tm*4+i)*1024 + cbase + tn*4) = acc4[i];
  }
}

// =============== K1: GEMM1 + softmax + region partial sums ================
// grid 392 (32 rows), block 256 (4 waves). BK=128, 16 iterations.
// Per iter: [ds_write A(k+1)] [B(k) 20 L2-loads] [A(k+2) 4 HBM loads LAST]
//           [4x(2 ds_read + 10 MFMA)] [lgkm-only barrier].
// B-wait leaves A(k+2) in flight (youngest); A write-stall amortized away.
__global__ __launch_bounds__(256, 2) void k1_main(
    const float* __restrict__ am, const u16* __restrict__ w1bp,
    float* __restrict__ partial)
{
  __shared__ __attribute__((aligned(16))) u16 sAbuf[2][32*128]; // 2 x 8 KB swizzled
  __shared__ float redM[32][4];
  __shared__ float redS[32][4];
  u16* const sb0 = &sAbuf[0][0];
  u16* const sb1 = &sAbuf[1][0];

  const int t = threadIdx.x, w = t >> 6, l = t & 63;
  const int llo = l & 15, lhi = l >> 4;
  const int blk = blockIdx.x;
  const int cb = w * 80;

  f32x4 acc[2][5];
#pragma unroll
  for (int m = 0; m < 2; ++m)
#pragma unroll
    for (int f = 0; f < 5; ++f) acc[m][f] = (f32x4){0.f,0.f,0.f,0.f};

  // A staging: thread -> row ar (0..31), 16-f32 chunk j (0..7) of 128-k slice
  const int ar = t >> 3, j = t & 7;
  const float4* aptr = (const float4*)(am + (size_t)(blk*32 + ar)*2048 + j*16);
  // LDS: row stride 256B (16 slots of 16B); slots 2j, 2j+1, XOR-swizzled low3
  const int aw0 = ar*256 + ((2*j  ) ^ (ar & 7))*16;   // byte offsets
  const int aw1 = ar*256 + ((2*j+1) ^ (ar & 7))*16;

  const u16* const bbase = w1bp + (size_t)(w*5)*512 + (size_t)l*8;

  // E holds A(even tiles), O holds A(odd tiles); 4 float4 each
  float4 E0, E1, E2, E3, O0, O1, O2, O3;
  E0 = aptr[0];  E1 = aptr[1];  E2 = aptr[2];  E3 = aptr[3];    // A(0)
  O0 = aptr[32]; O1 = aptr[33]; O2 = aptr[34]; O3 = aptr[35];   // A(1)
  *(short8*)((char*)sb0 + aw0) = pack8(E0, E1);
  *(short8*)((char*)sb0 + aw1) = pack8(E2, E3);
  LGKM_BARRIER();

#pragma unroll 1
  for (int k = 0; k < 16; ++k){
    u16* const cur = (k & 1) ? sb1 : sb0;
    u16* const nxt = (k & 1) ? sb0 : sb1;
    // 1) LDS-write A(k+1) from the set loaded 2 iters ago (no vm stall)
    if (k < 15){
      if (k & 1){
        *(short8*)((char*)nxt + aw0) = pack8(E0, E1);
        *(short8*)((char*)nxt + aw1) = pack8(E2, E3);
      } else {
        *(short8*)((char*)nxt + aw0) = pack8(O0, O1);
        *(short8*)((char*)nxt + aw1) = pack8(O2, O3);
      }
    }
    // 2) B(k): 20 fragment loads from L2 (issued before A so the B-wait
    //    leaves the A prefetch in flight)
    short8 bv0[5], bv1[5], bv2[5], bv3[5];
    {
      const u16* bp = bbase + (size_t)(4*k)*10240;
#pragma unroll
      for (int f = 0; f < 5; ++f) bv0[f] = *(const short8*)(bp + (size_t)f*512);
#pragma unroll
      for (int f = 0; f < 5; ++f) bv1[f] = *(const short8*)(bp + (size_t)(20+f)*512);
#pragma unroll
      for (int f = 0; f < 5; ++f) bv2[f] = *(const short8*)(bp + (size_t)(40+f)*512);
#pragma unroll
      for (int f = 0; f < 5; ++f) bv3[f] = *(const short8*)(bp + (size_t)(60+f)*512);
    }
    SB0();
    // 3) issue A(k+2) HBM loads (youngest in vm queue -> survive B-wait)
    if (k < 14){
      const float4* ap = aptr + (size_t)(k+2)*32;
      if (k & 1){ O0 = ap[0]; O1 = ap[1]; O2 = ap[2]; O3 = ap[3]; }
      else      { E0 = ap[0]; E1 = ap[1]; E2 = ap[2]; E3 = ap[3]; }
    }
    SB0();
    // 4) MFMA: 4 ksegs x (2 ds_read_b128 + 10 MFMA)
#pragma unroll
    for (int kk = 0; kk < 4; ++kk){
      const int jr = ((kk*4 + lhi) ^ (llo & 7)) * 16;
      short8 af0 = *(const short8*)((const char*)cur + llo*256 + jr);
      short8 af1 = *(const short8*)((const char*)cur + (16 + llo)*256 + jr);
      const short8* bv = (kk==0) ? bv0 : (kk==1) ? bv1 : (kk==2) ? bv2 : bv3;
#pragma unroll
      for (int f = 0; f < 5; ++f){
        acc[0][f] = MFMA16(af0, bv[f], acc[0][f]);
        acc[1][f] = MFMA16(af1, bv[f], acc[1][f]);
      }
    }
    LGKM_BARRIER();
  }

  // ---- epilogue: softmax over 320 cols, rows = m*16 + lhi*4 + r ----
  float rmax[2][4];
#pragma unroll
  for (int m = 0; m < 2; ++m)
#pragma unroll
    for (int r = 0; r < 4; ++r){
      float x = acc[m][0][r];
#pragma unroll
      for (int f = 1; f < 5; ++f) x = fmaxf(x, acc[m][f][r]);
      x = fmaxf(x, __shfl_xor(x, 1));
      x = fmaxf(x, __shfl_xor(x, 2));
      x = fmaxf(x, __shfl_xor(x, 4));
      x = fmaxf(x, __shfl_xor(x, 8));
      rmax[m][r] = x;
    }
  if (llo == 0){
#pragma unroll
    for (int m = 0; m < 2; ++m)
#pragma unroll
      for (int r = 0; r < 4; ++r)
        redM[m*16 + lhi*4 + r][w] = rmax[m][r];
  }
  __syncthreads();
#pragma unroll
  for (int m = 0; m < 2; ++m)
#pragma unroll
    for (int r = 0; r < 4; ++r){
      int row = m*16 + lhi*4 + r;
      rmax[m][r] = fmaxf(fmaxf(redM[row][0], redM[row][1]),
                         fmaxf(redM[row][2], redM[row][3]));
    }
  float rsum[2][4];
#pragma unroll
  for (int m = 0; m < 2; ++m)
#pragma unroll
    for (int r = 0; r < 4; ++r){
      float s = 0.f;
#pragma unroll
      for (int f = 0; f < 5; ++f){
        float e = __expf(acc[m][f][r] - rmax[m][r]);
        acc[m][f][r] = e; s += e;
      }
      s += __shfl_xor(s, 1);
      s += __shfl_xor(s, 2);
      s += __shfl_xor(s, 4);
      s += __shfl_xor(s, 8);
      rsum[m][r] = s;
    }
  if (llo == 0){
#pragma unroll
    for (int m = 0; m < 2; ++m)
#pragma unroll
      for (int r = 0; r < 4; ++r)
        redS[m*16 + lhi*4 + r][w] = rsum[m][r];
  }
  __syncthreads();
#pragma unroll
  for (int m = 0; m < 2; ++m)
#pragma unroll
    for (int r = 0; r < 4; ++r){
      int row = m*16 + lhi*4 + r;
      rmax[m][r] = 1.f / (redS[row][0] + redS[row][1] + redS[row][2] + redS[row][3]);
    }
  const int n0 = blk * 32;
  const int thr = 196 * (n0/196 + 1) - n0;     // rows < thr -> seg0
  float sseg0[5] = {0,0,0,0,0}, sseg1[5] = {0,0,0,0,0};
#pragma unroll
  for (int m = 0; m < 2; ++m)
#pragma unroll
    for (int r = 0; r < 4; ++r){
      int row = m*16 + lhi*4 + r;
      float sc = rmax[m][r];
      bool in0 = row < thr;
#pragma unroll
      for (int f = 0; f < 5; ++f){
        float v = acc[m][f][r] * sc;
        sseg0[f] += in0 ? v : 0.f;
        sseg1[f] += in0 ? 0.f : v;
      }
    }
#pragma unroll
  for (int f = 0; f < 5; ++f){
    sseg0[f] += __shfl_xor(sseg0[f], 16); sseg0[f] += __shfl_xor(sseg0[f], 32);
    sseg1[f] += __shfl_xor(sseg1[f], 16); sseg1[f] += __shfl_xor(sseg1[f], 32);
  }
  if (lhi == 0){
#pragma unroll
    for (int f = 0; f < 5; ++f){
      partial[blk*640 +       cb + f*16 + llo] = sseg0[f];
      partial[blk*640 + 320 + cb + f*16 + llo] = sseg1[f];
    }
  }
}

// =============== K2c: reduce partials + attr_dis@W2T + both softmax =======
__global__ __launch_bounds__(256) void k2c_final(
    const float* __restrict__ partialp, const float* __restrict__ W2T,
    const float* __restrict__ l3p, float* __restrict__ outp,
    float* __restrict__ out_ad)
{
  __shared__ __attribute__((aligned(16))) float sad[320];
  __shared__ float redA[4], redB[4];
  const int b = blockIdx.x, t = threadIdx.x;
  const int w = t >> 6, l = t & 63;
  const int lo = (196*b) >> 5, hi = (196*b + 195) >> 5;
  for (int i = t; i < 320; i += 256){
    float s = 0.f;
    for (int blk = lo; blk <= hi; ++blk){
      int seg = b - (blk*32)/196;
      if (seg >= 0 && seg < 2) s += partialp[blk*640 + seg*320 + i];
    }
    s *= (1.f / 320.f);
    sad[i] = s;
    out_ad[b*320 + i] = s;
  }
  __syncthreads();
  const int c0 = t * 4;
  f32x4 s2v = {0.f,0.f,0.f,0.f};
  const float4* a4 = (const float4*)sad;
#pragma unroll 4
  for (int i = 0; i < 80; ++i){
    float4 sv = a4[i];
    f32x4 w0 = *(const f32x4*)(W2T + (size_t)(4*i  )*1024 + c0);
    f32x4 w1 = *(const f32x4*)(W2T + (size_t)(4*i+1)*1024 + c0);
    f32x4 w2 = *(const f32x4*)(W2T + (size_t)(4*i+2)*1024 + c0);
    f32x4 w3 = *(const f32x4*)(W2T + (size_t)(4*i+3)*1024 + c0);
    s2v += sv.x*w0 + sv.y*w1 + sv.z*w2 + sv.w*w3;
  }
  f32x4 s3v = {0.f,0.f,0.f,0.f};
#pragma unroll
  for (int kg = 0; kg < 16; ++kg)
    s3v += *(const f32x4*)(l3p + (size_t)kg*65536 + b*1024 + c0);
  float l2a[4], l3a[4];
#pragma unroll
  for (int jj = 0; jj < 4; ++jj){
    bool valid = (c0 + jj) < 1000;
    l2a[jj] = valid ? s2v[jj] : -3.4e38f;
    l3a[jj] = valid ? s3v[jj] : -3.4e38f;
  }
  float m2 = fmaxf(fmaxf(l2a[0],l2a[1]), fmaxf(l2a[2],l2a[3]));
  float m3 = fmaxf(fmaxf(l3a[0],l3a[1]), fmaxf(l3a[2],l3a[3]));
#pragma unroll
  for (int off = 32; off > 0; off >>= 1){
    m2 = fmaxf(m2, __shfl_xor(m2, off));
    m3 = fmaxf(m3, __shfl_xor(m3, off));
  }
  if (l == 0){ redA[w] = m2; redB[w] = m3; }
  __syncthreads();
  m2 = fmaxf(fmaxf(redA[0],redA[1]), fmaxf(redA[2],redA[3]));
  m3 = fmaxf(fmaxf(redB[0],redB[1]), fmaxf(redB[2],redB[3]));
  __syncthreads();
  float e2[4], e3[4], s2 = 0.f, s3 = 0.f;
#pragma unroll
  for (int jj = 0; jj < 4; ++jj){
    bool valid = (c0 + jj) < 1000;
    e2[jj] = valid ? __expf(l2a[jj] - m2) : 0.f;
    e3[jj] = valid ? __expf(l3a[jj] - m3) : 0.f;
    s2 += e2[jj]; s3 += e3[jj];
  }
#pragma unroll
  for (int off = 32; off > 0; off >>= 1){
    s2 += __shfl_xor(s2, off);
    s3 += __shfl_xor(s3, off);
  }
  if (l == 0){ redA[w] = s2; redB[w] = s3; }
  __syncthreads();
  s2 = redA[0] + redA[1] + redA[2] + redA[3];
  s3 = redB[0] + redB[1] + redB[2] + redB[3];
  float i2 = 1.f / s2, i3 = 1.f / s3;
#pragma unroll
  for (int jj = 0; jj < 4; ++jj){
    int c = c0 + jj;
    if (c < 1000) outp[b*1000 + c] = 0.5f * (e2[jj]*i2 + e3[jj]*i3);
  }
}

extern "C" void kernel_launch(void* const* d_in, const int* in_sizes, int n_in,
                              void* d_out, int out_size, void* d_ws, size_t ws_size,
                              hipStream_t stream)
{
  const float* attr_map = (const float*)d_in[0];
  const float* features = (const float*)d_in[1];
  const float* W1 = (const float*)d_in[2];
  const float* W2 = (const float*)d_in[3];
  const float* W3 = (const float*)d_in[4];
  float* outp = (float*)d_out;

  char* ws = (char*)d_ws;
  u16*   w1bp    = (u16*)ws;                       // 1,310,720 B
  float* W2T     = (float*)(ws + 1310720);         // 1,310,720 B
  float* partial = (float*)(ws + 2621440);         // 1,003,520 B
  float* l3p     = (float*)(ws + 3624960);         // 4,194,304 B (total 7.8 MB)

  kprep    <<<896, 256, 0, stream>>>(W1, W2, features, W3, w1bp, W2T, l3p);
  k1_main  <<<392, 256, 0, stream>>>(attr_map, w1bp, partial);
  k2c_final<<<64, 256, 0, stream>>>(partial, W2T, l3p, outp, outp + 64000);
}